// Round 3
// baseline (396.237 us; speedup 1.0000x reference)
//
#include <hip/hip_runtime.h>
#include <stdint.h>

// Algebraic restructuring: only the cls token (n=0) queries, so K/V are never
// materialized.
//   logits_h[n] = (x0 . A_h . x_n)/8 + softmax-invariant const,  A_h = Wq_h Wk_h^T
//   r_h = x0 @ A_h + Wk_h bq_h   (per (b,s): 4096-vec)
//   p = softmax(r . x / 8);  y_h = sum_n p_h[n] x[n]
//   out = sum_h y_h @ G_h + bvo,  G_h = Wv_h @ Wo[h*64:(h+1)*64,:],  bvo = bv@Wo+bo
// All fp32 — absmax vs reference should be ~1e-5.

// ---------------- K1: A_h and G_h precompute ----------------
// grid (8 jt, 8 h, 2 mode). mode 0: A[k][h*512+j] = sum_c Wq[k][h64+c] Wk[j][h64+c]
//                            mode 1: G[h*512+k][j] = sum_c Wv[k][h64+c] Wo[h64+c][j]
__global__ __launch_bounds__(256) void prep_mats_kernel(
    const float* __restrict__ Wq, const float* __restrict__ Wk,
    const float* __restrict__ Wv, const float* __restrict__ Wo,
    float* __restrict__ A, float* __restrict__ G) {
  const int jt = blockIdx.x;
  const int h  = blockIdx.y;
  const int mode = blockIdx.z;
  const int t = threadIdx.x;
  const int j0 = jt * 64;

  __shared__ float p2_s[64][65];
  __shared__ float p1_s[64][65];

  if (mode == 0) {
#pragma unroll
    for (int l = 0; l < 4; ++l) {
      int flat4 = t + l * 256;
      int row = flat4 >> 4;
      int c4 = (flat4 & 15) * 4;
      float4 v = *(const float4*)&Wk[(long)(j0 + row) * 512 + h * 64 + c4];
      p2_s[row][c4] = v.x; p2_s[row][c4 + 1] = v.y;
      p2_s[row][c4 + 2] = v.z; p2_s[row][c4 + 3] = v.w;
    }
  } else {
#pragma unroll
    for (int l = 0; l < 4; ++l) {
      int flat4 = t + l * 256;
      int c = flat4 >> 4;
      int jj4 = (flat4 & 15) * 4;
      float4 v = *(const float4*)&Wo[(long)(h * 64 + c) * 512 + j0 + jj4];
      p2_s[jj4][c] = v.x; p2_s[jj4 + 1][c] = v.y;
      p2_s[jj4 + 2][c] = v.z; p2_s[jj4 + 3][c] = v.w;
    }
  }

  const float* P1 = (mode == 0) ? Wq : Wv;
  const int ko = (t >> 4) * 4;
  const int jo = (t & 15) * 4;

  for (int k0 = 0; k0 < 512; k0 += 64) {
    __syncthreads();
#pragma unroll
    for (int l = 0; l < 4; ++l) {
      int flat4 = t + l * 256;
      int row = flat4 >> 4;
      int c4 = (flat4 & 15) * 4;
      float4 v = *(const float4*)&P1[(long)(k0 + row) * 512 + h * 64 + c4];
      p1_s[row][c4] = v.x; p1_s[row][c4 + 1] = v.y;
      p1_s[row][c4 + 2] = v.z; p1_s[row][c4 + 3] = v.w;
    }
    __syncthreads();

    float acc[4][4] = {};
    for (int c = 0; c < 64; ++c) {
      float a0 = p1_s[ko][c], a1 = p1_s[ko + 1][c];
      float a2 = p1_s[ko + 2][c], a3 = p1_s[ko + 3][c];
      float b0 = p2_s[jo][c], b1 = p2_s[jo + 1][c];
      float b2 = p2_s[jo + 2][c], b3 = p2_s[jo + 3][c];
      acc[0][0] += a0 * b0; acc[0][1] += a0 * b1; acc[0][2] += a0 * b2; acc[0][3] += a0 * b3;
      acc[1][0] += a1 * b0; acc[1][1] += a1 * b1; acc[1][2] += a1 * b2; acc[1][3] += a1 * b3;
      acc[2][0] += a2 * b0; acc[2][1] += a2 * b1; acc[2][2] += a2 * b2; acc[2][3] += a2 * b3;
      acc[3][0] += a3 * b0; acc[3][1] += a3 * b1; acc[3][2] += a3 * b2; acc[3][3] += a3 * b3;
    }
#pragma unroll
    for (int e = 0; e < 4; ++e) {
      float4 v = make_float4(acc[e][0], acc[e][1], acc[e][2], acc[e][3]);
      if (mode == 0)
        *(float4*)&A[(long)(k0 + ko + e) * 4096 + h * 512 + j0 + jo] = v;
      else
        *(float4*)&G[((long)h * 512 + k0 + ko + e) * 512 + j0 + jo] = v;
    }
  }
}

// ---------------- K1b: bvec[h*512+j] = bq_h . Wk[j][h-cols]; bvo = bv@Wo + bo ----
__global__ __launch_bounds__(256) void prep_bias_kernel(
    const float* __restrict__ Wk, const float* __restrict__ Wo,
    const float* __restrict__ bq, const float* __restrict__ bv,
    const float* __restrict__ bo,
    float* __restrict__ bvec, float* __restrict__ bvo) {
  int idx = blockIdx.x * 256 + threadIdx.x;
  if (idx < 4096) {
    int h = idx >> 9, j = idx & 511;
    float s = 0.f;
#pragma unroll 8
    for (int c = 0; c < 64; ++c) s += bq[h * 64 + c] * Wk[(long)j * 512 + h * 64 + c];
    bvec[idx] = s;
  } else if (idx < 4608) {
    int j = idx - 4096;
    float s = bo[j];
#pragma unroll 8
    for (int k = 0; k < 512; ++k) s += bv[k] * Wo[(long)k * 512 + j];
    bvo[j] = s;
  }
}

// ---------------- K2: r_all[256][4096] = X0 @ A + bvec ----------------
// grid (32 jt of 128 cols, 8 it of 32 rows)
__global__ __launch_bounds__(256) void rproj_kernel(
    const float* __restrict__ x, const float* __restrict__ A,
    const float* __restrict__ bvec, float* __restrict__ r_all) {
  const int jt = blockIdx.x;
  const int it = blockIdx.y;
  const int t = threadIdx.x;
  __shared__ float x0_s[32][65];

  const int jj = jt * 128 + (t & 31) * 4;
  const int rg = (t >> 5) * 4;
  float4 acc[4] = {};

  for (int k0 = 0; k0 < 512; k0 += 64) {
    __syncthreads();
#pragma unroll
    for (int l = 0; l < 2; ++l) {
      int flat4 = t + l * 256;
      int row = flat4 >> 4;
      int c4 = (flat4 & 15) * 4;
      float4 v = *(const float4*)&x[((long)(it * 32 + row) * 256) * 512 + k0 + c4];
      x0_s[row][c4] = v.x; x0_s[row][c4 + 1] = v.y;
      x0_s[row][c4 + 2] = v.z; x0_s[row][c4 + 3] = v.w;
    }
    __syncthreads();
    for (int k = 0; k < 64; ++k) {
      float4 av = *(const float4*)&A[(long)(k0 + k) * 4096 + jj];
      float x0v = x0_s[rg][k], x1v = x0_s[rg + 1][k];
      float x2v = x0_s[rg + 2][k], x3v = x0_s[rg + 3][k];
      acc[0].x += x0v * av.x; acc[0].y += x0v * av.y; acc[0].z += x0v * av.z; acc[0].w += x0v * av.w;
      acc[1].x += x1v * av.x; acc[1].y += x1v * av.y; acc[1].z += x1v * av.z; acc[1].w += x1v * av.w;
      acc[2].x += x2v * av.x; acc[2].y += x2v * av.y; acc[2].z += x2v * av.z; acc[2].w += x2v * av.w;
      acc[3].x += x3v * av.x; acc[3].y += x3v * av.y; acc[3].z += x3v * av.z; acc[3].w += x3v * av.w;
    }
  }
  float4 bv4 = *(const float4*)&bvec[jj];
#pragma unroll
  for (int e = 0; e < 4; ++e) {
    float4 v = make_float4(acc[e].x + bv4.x, acc[e].y + bv4.y,
                           acc[e].z + bv4.z, acc[e].w + bv4.w);
    *(float4*)&r_all[(long)(it * 32 + rg + e) * 4096 + jj] = v;
  }
}

// ---------------- K3: fused logits + softmax + y, one WG per (b,s) ----------------
__global__ __launch_bounds__(256) void attn_fused_kernel(
    const float* __restrict__ x, const float* __restrict__ r_all,
    float* __restrict__ Y) {
  const int bs = blockIdx.x;
  const int t = threadIdx.x;
  __shared__ float r_s[4096];
  __shared__ float p_s[8][256];

#pragma unroll
  for (int l = 0; l < 4; ++l) {
    int i4 = (t + l * 256) * 4;
    *(float4*)&r_s[i4] = *(const float4*)&r_all[(long)bs * 4096 + i4];
  }
  __syncthreads();

  // pass 1: thread t = token t
  {
    const float* xrow = x + ((long)bs * 256 + t) * 512;
    float dots[8] = {};
    for (int k0 = 0; k0 < 512; k0 += 4) {
      float4 xv = *(const float4*)&xrow[k0];
#pragma unroll
      for (int h = 0; h < 8; ++h) {
        float4 rv = *(const float4*)&r_s[h * 512 + k0];
        dots[h] += xv.x * rv.x + xv.y * rv.y + xv.z * rv.z + xv.w * rv.w;
      }
    }
#pragma unroll
    for (int h = 0; h < 8; ++h) p_s[h][t] = dots[h] * 0.125f;
  }
  __syncthreads();

  // softmax per head: wave g handles heads 2g, 2g+1
  {
    const int g = t >> 6, lane = t & 63;
#pragma unroll
    for (int hh = 0; hh < 2; ++hh) {
      const int h = g * 2 + hh;
      float l0 = p_s[h][lane], l1 = p_s[h][lane + 64];
      float l2 = p_s[h][lane + 128], l3 = p_s[h][lane + 192];
      float m = fmaxf(fmaxf(l0, l1), fmaxf(l2, l3));
      for (int o = 32; o; o >>= 1) m = fmaxf(m, __shfl_xor(m, o));
      float e0 = __expf(l0 - m), e1 = __expf(l1 - m);
      float e2 = __expf(l2 - m), e3 = __expf(l3 - m);
      float s = e0 + e1 + e2 + e3;
      for (int o = 32; o; o >>= 1) s += __shfl_xor(s, o);
      const float inv = 1.f / s;
      p_s[h][lane] = e0 * inv; p_s[h][lane + 64] = e1 * inv;
      p_s[h][lane + 128] = e2 * inv; p_s[h][lane + 192] = e3 * inv;
    }
  }
  __syncthreads();

  // pass 2: Y[bs][h*512 + d] = sum_n p[h][n] x[n][d]; thread owns d0 = 2t
  {
    const int d0 = t * 2;
    float2 acc[8] = {};
    const float* xb = x + (long)bs * 256 * 512 + d0;
    for (int n = 0; n < 256; n += 2) {
      float2 xv0 = *(const float2*)&xb[(long)n * 512];
      float2 xv1 = *(const float2*)&xb[(long)(n + 1) * 512];
#pragma unroll
      for (int h = 0; h < 8; ++h) {
        float2 pp = *(const float2*)&p_s[h][n];
        acc[h].x += pp.x * xv0.x + pp.y * xv1.x;
        acc[h].y += pp.x * xv0.y + pp.y * xv1.y;
      }
    }
#pragma unroll
    for (int h = 0; h < 8; ++h)
      *(float2*)&Y[(long)bs * 4096 + h * 512 + d0] = acc[h];
  }
}

// ---------------- K4: part[ks] = Y[:, kslice] @ G[kslice, :] ----------------
// grid (8 jt of 64 cols, 4 it of 64 rows, 8 ks of 512 k)
__global__ __launch_bounds__(256) void oproj_kernel(
    const float* __restrict__ Y, const float* __restrict__ G,
    float* __restrict__ part) {
  const int jt = blockIdx.x;
  const int it = blockIdx.y;
  const int ks = blockIdx.z;
  const int t = threadIdx.x;
  const int j0 = jt * 64, r0 = it * 64, k0 = ks * 512;

  __shared__ float y_s[64][65];
  const int jj = j0 + (t & 15) * 4;
  const int rg = (t >> 4) * 4;
  float4 acc[4] = {};

  for (int kk0 = 0; kk0 < 512; kk0 += 64) {
    __syncthreads();
#pragma unroll
    for (int l = 0; l < 4; ++l) {
      int flat4 = t + l * 256;
      int row = flat4 >> 4;
      int c4 = (flat4 & 15) * 4;
      float4 v = *(const float4*)&Y[(long)(r0 + row) * 4096 + k0 + kk0 + c4];
      y_s[row][c4] = v.x; y_s[row][c4 + 1] = v.y;
      y_s[row][c4 + 2] = v.z; y_s[row][c4 + 3] = v.w;
    }
    __syncthreads();
    for (int k = 0; k < 64; ++k) {
      float4 gv = *(const float4*)&G[(long)(k0 + kk0 + k) * 512 + jj];
      float y0 = y_s[rg][k], y1 = y_s[rg + 1][k];
      float y2 = y_s[rg + 2][k], y3 = y_s[rg + 3][k];
      acc[0].x += y0 * gv.x; acc[0].y += y0 * gv.y; acc[0].z += y0 * gv.z; acc[0].w += y0 * gv.w;
      acc[1].x += y1 * gv.x; acc[1].y += y1 * gv.y; acc[1].z += y1 * gv.z; acc[1].w += y1 * gv.w;
      acc[2].x += y2 * gv.x; acc[2].y += y2 * gv.y; acc[2].z += y2 * gv.z; acc[2].w += y2 * gv.w;
      acc[3].x += y3 * gv.x; acc[3].y += y3 * gv.y; acc[3].z += y3 * gv.z; acc[3].w += y3 * gv.w;
    }
  }
#pragma unroll
  for (int e = 0; e < 4; ++e)
    *(float4*)&part[((long)ks * 256 + r0 + rg + e) * 512 + jj] = acc[e];
}

// ---------------- K5: out = sum_ks part[ks] + bvo ----------------
__global__ __launch_bounds__(256) void oproj_reduce_kernel(
    const float* __restrict__ part, const float* __restrict__ bvo,
    float* __restrict__ out) {
  int idx = blockIdx.x * 256 + threadIdx.x;   // 0..131071
  float s = bvo[idx & 511];
#pragma unroll
  for (int ks = 0; ks < 8; ++ks) s += part[(long)ks * 131072 + idx];
  out[idx] = s;
}

extern "C" void kernel_launch(void* const* d_in, const int* in_sizes, int n_in,
                              void* d_out, int out_size, void* d_ws, size_t ws_size,
                              hipStream_t stream) {
  (void)in_sizes; (void)n_in; (void)out_size; (void)ws_size;
  const float* x  = (const float*)d_in[0];
  const float* Wq = (const float*)d_in[1];
  const float* bq = (const float*)d_in[2];
  const float* Wk = (const float*)d_in[3];
  const float* bk = (const float*)d_in[4];  (void)bk;  // softmax-invariant, dropped
  const float* Wv = (const float*)d_in[5];
  const float* bv = (const float*)d_in[6];
  const float* Wo = (const float*)d_in[7];
  const float* bo = (const float*)d_in[8];
  float* out = (float*)d_out;

  float* A    = (float*)d_ws;          // 512*4096      = 8 MiB
  float* G    = A + 2097152;           // 4096*512      = 8 MiB
  float* bvec = G + 2097152;           // 4096
  float* bvo  = bvec + 4096;           // 512
  float* r    = bvo + 512;             // 256*4096      = 4 MiB
  float* Y    = r + 1048576;           // 256*4096      = 4 MiB
  float* part = Y + 1048576;           // 8*256*512     = 4 MiB

  prep_mats_kernel<<<dim3(8, 8, 2), 256, 0, stream>>>(Wq, Wk, Wv, Wo, A, G);
  prep_bias_kernel<<<18, 256, 0, stream>>>(Wk, Wo, bq, bv, bo, bvec, bvo);
  rproj_kernel<<<dim3(32, 8), 256, 0, stream>>>(x, A, bvec, r);
  attn_fused_kernel<<<256, 256, 0, stream>>>(x, r, Y);
  oproj_kernel<<<dim3(8, 4, 8), 256, 0, stream>>>(Y, G, part);
  oproj_reduce_kernel<<<512, 256, 0, stream>>>(part, bvo, out);
}

// Round 4
// 340.551 us; speedup vs baseline: 1.1635x; 1.1635x over previous
//
#include <hip/hip_runtime.h>
#include <stdint.h>

// Algebra (validated R3): only cls token queries ->
//   A_h = Wq_h Wk_h^T ; r = x0 @ A + bvec ; logits = (r . x)/8 ; p = softmax
//   y_h = sum_n p_h[n] x[n] ; out = sum_h y_h @ G_h + bvo
// R4: same math, rebuilt for occupancy (>=4 blocks/CU on every kernel).

// ---------------- K1: A_h / G_h precompute. grid (8 jt, 8 h, 16 = mode*8+k0) ----
__global__ __launch_bounds__(256) void prep_mats_kernel(
    const float* __restrict__ Wq, const float* __restrict__ Wk,
    const float* __restrict__ Wv, const float* __restrict__ Wo,
    float* __restrict__ A, float* __restrict__ G) {
  const int jt = blockIdx.x;
  const int h  = blockIdx.y;
  const int mode = blockIdx.z >> 3;
  const int k0 = (blockIdx.z & 7) * 64;
  const int t = threadIdx.x;
  const int j0 = jt * 64;

  __shared__ float p2_s[64][65];
  __shared__ float p1_s[64][65];

  if (mode == 0) {
#pragma unroll
    for (int l = 0; l < 4; ++l) {
      int flat4 = t + l * 256;
      int row = flat4 >> 4;
      int c4 = (flat4 & 15) * 4;
      float4 v = *(const float4*)&Wk[(long)(j0 + row) * 512 + h * 64 + c4];
      p2_s[row][c4] = v.x; p2_s[row][c4 + 1] = v.y;
      p2_s[row][c4 + 2] = v.z; p2_s[row][c4 + 3] = v.w;
    }
  } else {
#pragma unroll
    for (int l = 0; l < 4; ++l) {
      int flat4 = t + l * 256;
      int c = flat4 >> 4;
      int jj4 = (flat4 & 15) * 4;
      float4 v = *(const float4*)&Wo[(long)(h * 64 + c) * 512 + j0 + jj4];
      p2_s[jj4][c] = v.x; p2_s[jj4 + 1][c] = v.y;
      p2_s[jj4 + 2][c] = v.z; p2_s[jj4 + 3][c] = v.w;
    }
  }

  const float* P1 = (mode == 0) ? Wq : Wv;
#pragma unroll
  for (int l = 0; l < 4; ++l) {
    int flat4 = t + l * 256;
    int row = flat4 >> 4;
    int c4 = (flat4 & 15) * 4;
    float4 v = *(const float4*)&P1[(long)(k0 + row) * 512 + h * 64 + c4];
    p1_s[row][c4] = v.x; p1_s[row][c4 + 1] = v.y;
    p1_s[row][c4 + 2] = v.z; p1_s[row][c4 + 3] = v.w;
  }
  __syncthreads();

  const int ko = (t >> 4) * 4;
  const int jo = (t & 15) * 4;
  float acc[4][4] = {};
  for (int c = 0; c < 64; ++c) {
    float a0 = p1_s[ko][c], a1 = p1_s[ko + 1][c];
    float a2 = p1_s[ko + 2][c], a3 = p1_s[ko + 3][c];
    float b0 = p2_s[jo][c], b1 = p2_s[jo + 1][c];
    float b2 = p2_s[jo + 2][c], b3 = p2_s[jo + 3][c];
    acc[0][0] += a0 * b0; acc[0][1] += a0 * b1; acc[0][2] += a0 * b2; acc[0][3] += a0 * b3;
    acc[1][0] += a1 * b0; acc[1][1] += a1 * b1; acc[1][2] += a1 * b2; acc[1][3] += a1 * b3;
    acc[2][0] += a2 * b0; acc[2][1] += a2 * b1; acc[2][2] += a2 * b2; acc[2][3] += a2 * b3;
    acc[3][0] += a3 * b0; acc[3][1] += a3 * b1; acc[3][2] += a3 * b2; acc[3][3] += a3 * b3;
  }
#pragma unroll
  for (int e = 0; e < 4; ++e) {
    float4 v = make_float4(acc[e][0], acc[e][1], acc[e][2], acc[e][3]);
    if (mode == 0)
      *(float4*)&A[(long)(k0 + ko + e) * 4096 + h * 512 + j0 + jo] = v;
    else
      *(float4*)&G[((long)h * 512 + k0 + ko + e) * 512 + j0 + jo] = v;
  }
}

// ---------------- K1b: bvec, bvo ----------------
__global__ __launch_bounds__(256) void prep_bias_kernel(
    const float* __restrict__ Wk, const float* __restrict__ Wo,
    const float* __restrict__ bq, const float* __restrict__ bv,
    const float* __restrict__ bo,
    float* __restrict__ bvec, float* __restrict__ bvo) {
  int idx = blockIdx.x * 256 + threadIdx.x;
  if (idx < 4096) {
    int h = idx >> 9, j = idx & 511;
    float s = 0.f;
#pragma unroll 8
    for (int c = 0; c < 64; ++c) s += bq[h * 64 + c] * Wk[(long)j * 512 + h * 64 + c];
    bvec[idx] = s;
  } else if (idx < 4608) {
    int j = idx - 4096;
    float s = bo[j];
#pragma unroll 8
    for (int k = 0; k < 512; ++k) s += bv[k] * Wo[(long)k * 512 + j];
    bvo[j] = s;
  }
}

// ---------------- K2: r[256][4096] = X0 @ A + bvec. grid (32 jt, 16 it) --------
__global__ __launch_bounds__(256) void rproj_kernel(
    const float* __restrict__ x, const float* __restrict__ A,
    const float* __restrict__ bvec, float* __restrict__ r_all) {
  const int jt = blockIdx.x;
  const int it = blockIdx.y;
  const int t = threadIdx.x;
  __shared__ float x0_s[16 * 64];

  const int jj = jt * 128 + (t & 31) * 4;
  const int rg = t >> 5;           // 0..7, owns rows rg*2, rg*2+1
  float4 acc[2] = {};

  for (int k0 = 0; k0 < 512; k0 += 64) {
    __syncthreads();
    {
      int row = t >> 4;
      int c4 = (t & 15) * 4;
      float4 v = *(const float4*)&x[((long)(it * 16 + row) * 256) * 512 + k0 + c4];
      x0_s[row * 64 + c4] = v.x; x0_s[row * 64 + c4 + 1] = v.y;
      x0_s[row * 64 + c4 + 2] = v.z; x0_s[row * 64 + c4 + 3] = v.w;
    }
    __syncthreads();
    for (int k = 0; k < 64; ++k) {
      float4 av = *(const float4*)&A[(long)(k0 + k) * 4096 + jj];
      float x0v = x0_s[(rg * 2) * 64 + k];
      float x1v = x0_s[(rg * 2 + 1) * 64 + k];
      acc[0].x += x0v * av.x; acc[0].y += x0v * av.y; acc[0].z += x0v * av.z; acc[0].w += x0v * av.w;
      acc[1].x += x1v * av.x; acc[1].y += x1v * av.y; acc[1].z += x1v * av.z; acc[1].w += x1v * av.w;
    }
  }
  float4 bv4 = *(const float4*)&bvec[jj];
#pragma unroll
  for (int e = 0; e < 2; ++e) {
    float4 v = make_float4(acc[e].x + bv4.x, acc[e].y + bv4.y,
                           acc[e].z + bv4.z, acc[e].w + bv4.w);
    *(float4*)&r_all[(long)(it * 16 + rg * 2 + e) * 4096 + jj] = v;
  }
}

// ---------------- K3: logits. grid (256 bs, 4 nt), wave-per-token --------------
// L[bs][h][n] = (r[bs][h] . x[bs][n]) / 8
__global__ __launch_bounds__(256) void logits_kernel(
    const float* __restrict__ x, const float* __restrict__ r_all,
    float* __restrict__ L) {
  const int bs = blockIdx.x;
  const int nt = blockIdx.y;
  const int t = threadIdx.x;
  const int w = t >> 6, lane = t & 63;

  // r fragment in registers: rv[h][j] = r[bs][h*512 + lane*8 + j]
  float rv[8][8];
  const float* rb = r_all + (long)bs * 4096 + lane * 8;
#pragma unroll
  for (int h = 0; h < 8; ++h) {
    float4 a = *(const float4*)&rb[h * 512];
    float4 b = *(const float4*)&rb[h * 512 + 4];
    rv[h][0] = a.x; rv[h][1] = a.y; rv[h][2] = a.z; rv[h][3] = a.w;
    rv[h][4] = b.x; rv[h][5] = b.y; rv[h][6] = b.z; rv[h][7] = b.w;
  }

  for (int i = 0; i < 16; ++i) {
    const int n = nt * 64 + w * 16 + i;
    const float* xr = x + ((long)bs * 256 + n) * 512 + lane * 8;
    float4 xa = *(const float4*)xr;
    float4 xb = *(const float4*)(xr + 4);
    float acc[8];
#pragma unroll
    for (int h = 0; h < 8; ++h)
      acc[h] = xa.x * rv[h][0] + xa.y * rv[h][1] + xa.z * rv[h][2] + xa.w * rv[h][3]
             + xb.x * rv[h][4] + xb.y * rv[h][5] + xb.z * rv[h][6] + xb.w * rv[h][7];
#pragma unroll
    for (int h = 0; h < 8; ++h)
      for (int off = 32; off; off >>= 1)
        acc[h] += __shfl_xor(acc[h], off);
    if (lane < 8) {
      float v = acc[0];
#pragma unroll
      for (int h = 1; h < 8; ++h) v = (lane == h) ? acc[h] : v;
      L[((long)bs * 8 + lane) * 256 + n] = v * 0.125f;
    }
  }
}

// ---------------- K4: softmax (in-block) + Y. grid (256 bs, 4 dt), 128 thr -----
// Y[bs][h*512+d] = sum_n softmax(L[bs][h])[n] * x[bs][n][d]
__global__ __launch_bounds__(128) void y_kernel(
    const float* __restrict__ x, const float* __restrict__ L,
    float* __restrict__ Y) {
  const int bs = blockIdx.x;
  const int dt = blockIdx.y;
  const int t = threadIdx.x;
  const int w = t >> 6, lane = t & 63;
  __shared__ float p_s[8][256];

  // softmax: wave w handles heads 4w..4w+3; lane owns 4 logits
#pragma unroll
  for (int hh = 0; hh < 4; ++hh) {
    const int h = w * 4 + hh;
    float4 l4 = *(const float4*)&L[((long)bs * 8 + h) * 256 + lane * 4];
    float m = fmaxf(fmaxf(l4.x, l4.y), fmaxf(l4.z, l4.w));
    for (int o = 32; o; o >>= 1) m = fmaxf(m, __shfl_xor(m, o));
    float e0 = __expf(l4.x - m), e1 = __expf(l4.y - m);
    float e2 = __expf(l4.z - m), e3 = __expf(l4.w - m);
    float s = e0 + e1 + e2 + e3;
    for (int o = 32; o; o >>= 1) s += __shfl_xor(s, o);
    const float inv = 1.f / s;
    float4 p4 = make_float4(e0 * inv, e1 * inv, e2 * inv, e3 * inv);
    *(float4*)&p_s[h][lane * 4] = p4;
  }
  __syncthreads();

  const int d = dt * 128 + t;
  float acc[8] = {};
  const float* xb = x + (long)bs * 256 * 512 + d;
  for (int n0 = 0; n0 < 256; n0 += 4) {
    float xv0 = xb[(long)(n0 + 0) * 512];
    float xv1 = xb[(long)(n0 + 1) * 512];
    float xv2 = xb[(long)(n0 + 2) * 512];
    float xv3 = xb[(long)(n0 + 3) * 512];
#pragma unroll
    for (int h = 0; h < 8; ++h) {
      float4 p4 = *(const float4*)&p_s[h][n0];
      acc[h] += p4.x * xv0 + p4.y * xv1 + p4.z * xv2 + p4.w * xv3;
    }
  }
#pragma unroll
  for (int h = 0; h < 8; ++h)
    Y[(long)bs * 4096 + h * 512 + d] = acc[h];
}

// ---------------- K5: part[ks] = Y[:, kslice] @ G[kslice, :] -------------------
// grid (8 jt x 64 cols, 8 it x 32 rows, 16 ks x 256 k)
__global__ __launch_bounds__(256) void oproj_kernel(
    const float* __restrict__ Y, const float* __restrict__ G,
    float* __restrict__ part) {
  const int jt = blockIdx.x;
  const int it = blockIdx.y;
  const int ks = blockIdx.z;
  const int t = threadIdx.x;

  __shared__ float y_s[32 * 64];
  const int jj = jt * 64 + (t & 15) * 4;
  const int rg = t >> 4;           // 0..15, owns rows rg*2, rg*2+1
  float4 acc[2] = {};

  for (int kk0 = 0; kk0 < 256; kk0 += 64) {
    __syncthreads();
#pragma unroll
    for (int l = 0; l < 2; ++l) {
      int flat4 = t + l * 256;
      int row = flat4 >> 4;
      int c4 = (flat4 & 15) * 4;
      float4 v = *(const float4*)&Y[(long)(it * 32 + row) * 4096 + ks * 256 + kk0 + c4];
      y_s[row * 64 + c4] = v.x; y_s[row * 64 + c4 + 1] = v.y;
      y_s[row * 64 + c4 + 2] = v.z; y_s[row * 64 + c4 + 3] = v.w;
    }
    __syncthreads();
    for (int k = 0; k < 64; ++k) {
      float4 gv = *(const float4*)&G[(long)(ks * 256 + kk0 + k) * 512 + jj];
      float y0 = y_s[(rg * 2) * 64 + k];
      float y1 = y_s[(rg * 2 + 1) * 64 + k];
      acc[0].x += y0 * gv.x; acc[0].y += y0 * gv.y; acc[0].z += y0 * gv.z; acc[0].w += y0 * gv.w;
      acc[1].x += y1 * gv.x; acc[1].y += y1 * gv.y; acc[1].z += y1 * gv.z; acc[1].w += y1 * gv.w;
    }
  }
#pragma unroll
  for (int e = 0; e < 2; ++e)
    *(float4*)&part[((long)ks * 256 + it * 32 + rg * 2 + e) * 512 + jj] = acc[e];
}

// ---------------- K6: out = sum_ks part[ks] + bvo ------------------------------
__global__ __launch_bounds__(256) void oproj_reduce_kernel(
    const float* __restrict__ part, const float* __restrict__ bvo,
    float* __restrict__ out) {
  int idx = blockIdx.x * 256 + threadIdx.x;   // 0..131071
  float s = bvo[idx & 511];
#pragma unroll
  for (int ks = 0; ks < 16; ++ks) s += part[(long)ks * 131072 + idx];
  out[idx] = s;
}

extern "C" void kernel_launch(void* const* d_in, const int* in_sizes, int n_in,
                              void* d_out, int out_size, void* d_ws, size_t ws_size,
                              hipStream_t stream) {
  (void)in_sizes; (void)n_in; (void)out_size; (void)ws_size;
  const float* x  = (const float*)d_in[0];
  const float* Wq = (const float*)d_in[1];
  const float* bq = (const float*)d_in[2];
  const float* Wk = (const float*)d_in[3];
  const float* bk = (const float*)d_in[4];  (void)bk;  // softmax-invariant
  const float* Wv = (const float*)d_in[5];
  const float* bv = (const float*)d_in[6];
  const float* Wo = (const float*)d_in[7];
  const float* bo = (const float*)d_in[8];
  float* out = (float*)d_out;

  float* A    = (float*)d_ws;          // 512*4096   = 8 MiB
  float* G    = A + 2097152;           // 4096*512   = 8 MiB
  float* bvec = G + 2097152;           // 4096
  float* bvo  = bvec + 4096;           // 512
  float* r    = bvo + 512;             // 256*4096   = 4 MiB
  float* L    = r + 1048576;           // 256*8*256  = 2 MiB
  float* Y    = L + 524288;            // 256*4096   = 4 MiB
  float* part = Y + 1048576;           // 16*256*512 = 8 MiB

  prep_mats_kernel<<<dim3(8, 8, 16), 256, 0, stream>>>(Wq, Wk, Wv, Wo, A, G);
  prep_bias_kernel<<<18, 256, 0, stream>>>(Wk, Wo, bq, bv, bo, bvec, bvo);
  rproj_kernel<<<dim3(32, 16), 256, 0, stream>>>(x, A, bvec, r);
  logits_kernel<<<dim3(256, 4), 256, 0, stream>>>(x, r, L);
  y_kernel<<<dim3(256, 4), 128, 0, stream>>>(x, L, Y);
  oproj_kernel<<<dim3(8, 8, 16), 256, 0, stream>>>(Y, G, part);
  oproj_reduce_kernel<<<512, 256, 0, stream>>>(part, bvo, out);
}